// Round 5
// baseline (29.815 us; speedup 1.0000x reference)
//
#include <hip/hip_runtime.h>
#include <hip/hip_bf16.h>

// LDPC normalized min-sum decoder, B=8, M=1024 checks, N=2048 vars, deg<=~11.
// Round 4 -> 5: decode is LDS-latency-bound (VALUBusy 0.3%, one serial
// gather->min->scatter chain per iteration). Fix via ILP: 2 batches per block
// (two independent chains per thread interleave under LDS latency), peel
// iteration 0 (cv=0, acc=0 -> no gather, no leading barrier), skip the dead
// accumulator reset on the final iteration.

#define M_CHECK 1024
#define N_VAR   2048
#define BATCH   8
#define BPB     2                // batches per block
#define MAXD    12               // max check-row degree (actual <= ~11)
#define NUM_ITERS 5
#define FXS 16384.0f             // Q14 fixed-point scale
#define FXI (1.0f / 16384.0f)

// ---------------------------------------------------------------------------
// Kernel A: wave-per-row ordered compaction of dense H -> deg, row_cols_T
// (column-major [MAXD][M] for coalesced decode loads). int4-vectorized,
// deterministic ballot/popcount ranking.
__global__ __launch_bounds__(256) void build_rows_kernel(
    const int* __restrict__ H, int* __restrict__ deg,
    int* __restrict__ row_cols_T)
{
    const int m    = blockIdx.x * 4 + (threadIdx.x >> 6);   // wave per row
    const int lane = threadIdx.x & 63;
    const unsigned long long below = (1ULL << lane) - 1ULL;
    const int4* __restrict__ H4 = (const int4*)(H + m * N_VAR);

    int base = 0;
    for (int c = 0; c < N_VAR; c += 256) {                  // 256 cols per pass
        int4 h = H4[(c >> 2) + lane];
        unsigned long long m0 = __ballot(h.x != 0);
        unsigned long long m1 = __ballot(h.y != 0);
        unsigned long long m2 = __ballot(h.z != 0);
        unsigned long long m3 = __ballot(h.w != 0);
        int pb = __popcll(m0 & below) + __popcll(m1 & below)
               + __popcll(m2 & below) + __popcll(m3 & below);
        int b0 = (int)((m0 >> lane) & 1);
        int b1 = (int)((m1 >> lane) & 1);
        int b2 = (int)((m2 >> lane) & 1);
        int col = c + 4 * lane;
        int r = base + pb;
        if (h.x) { if (r < MAXD) row_cols_T[r * M_CHECK + m] = col; }
        r += b0;
        if (h.y) { if (r < MAXD) row_cols_T[r * M_CHECK + m] = col + 1; }
        r += b1;
        if (h.z) { if (r < MAXD) row_cols_T[r * M_CHECK + m] = col + 2; }
        r += b2;
        if (h.w) { if (r < MAXD) row_cols_T[r * M_CHECK + m] = col + 3; }
        base += __popcll(m0) + __popcll(m1) + __popcll(m2) + __popcll(m3);
    }
    if (lane == 0) deg[m] = (base < MAXD) ? base : MAXD;
}

// ---------------------------------------------------------------------------
// Kernel B: full decode, 2 batches per block. Thread t owns check row t and
// variable columns t, t+1024 for both batches. cv in registers; column sums
// via Q14 integer LDS atomics into 3 rotating accumulators per batch.
__global__ __launch_bounds__(1024) void decode_kernel(
    const float* __restrict__ soft_input, const float* __restrict__ check_weight,
    const int* __restrict__ deg, const int* __restrict__ row_cols_T,
    float* __restrict__ out)
{
    __shared__ int   acc[BPB][3][N_VAR];    // 48 KB fixed-point column sums
    __shared__ float soft_s[BPB][N_VAR];    // 16 KB

    const int b0 = blockIdx.x * BPB;
    const int t  = threadIdx.x;
    const float alpha = log1pf(expf(check_weight[0]));   // softplus(w)

    const int n0 = t, n1 = t + 1024;
    const float s00 = soft_input[ b0      * N_VAR + n0];
    const float s01 = soft_input[ b0      * N_VAR + n1];
    const float s10 = soft_input[(b0 + 1) * N_VAR + n0];
    const float s11 = soft_input[(b0 + 1) * N_VAR + n1];
    soft_s[0][n0] = s00;  soft_s[0][n1] = s01;
    soft_s[1][n0] = s10;  soft_s[1][n1] = s11;
#pragma unroll
    for (int q = 0; q < 3; ++q) {
        acc[0][q][n0] = 0; acc[0][q][n1] = 0;
        acc[1][q][n0] = 0; acc[1][q][n1] = 0;
    }

    const int dm = deg[t];
    int cols[MAXD];
#pragma unroll
    for (int d = 0; d < MAXD; ++d)
        cols[d] = (d < dm) ? row_cols_T[d * M_CHECK + t] : 0;   // coalesced
    __syncthreads();

    // per-edge soft inputs for both batches (registers; one-time LDS gather)
    float softc[BPB][MAXD];
#pragma unroll
    for (int d = 0; d < MAXD; ++d) {
        softc[0][d] = (d < dm) ? soft_s[0][cols[d]] : 0.f;
        softc[1][d] = (d < dm) ? soft_s[1][cols[d]] : 0.f;
    }

    float cv[BPB][MAXD];

    // ---- iteration 0 (peeled): cv=0 and acc=0, so vc = softc. No gather.
#pragma unroll
    for (int p = 0; p < BPB; ++p) {
        float mn1 = 1e38f, mn2 = 1e38f;
        unsigned sx = 0u;  bool zr = false;
#pragma unroll
        for (int d = 0; d < MAXD; ++d) {
            if (d < dm) {
                float vc = softc[p][d];
                float a  = fminf(fabsf(vc), 1e30f);
                if (a < mn1) { mn2 = mn1; mn1 = a; }
                else if (a < mn2) { mn2 = a; }
                sx ^= (__float_as_uint(vc) & 0x80000000u);
                zr |= (vc == 0.f);
            }
        }
        const float zmul = zr ? 0.f : alpha;
#pragma unroll
        for (int d = 0; d < MAXD; ++d) {
            if (d < dm) {
                float vc  = softc[p][d];
                float a   = fminf(fabsf(vc), 1e30f);
                float res = (a > mn1) ? mn1 : mn2;         // exclude-self min
                unsigned o = sx ^ (__float_as_uint(vc) & 0x80000000u);
                float v   = res * zmul;                    // >= 0
                float cvn = __uint_as_float(__float_as_uint(v) ^ o);
                cv[p][d] = cvn;
                atomicAdd(&acc[p][1][cols[d]], __float2int_rn(cvn * FXS));
            }
        }
    }
    __syncthreads();

    // ---- iterations 1..4: gather acc[it%3], scatter acc[(it+1)%3],
    //      reset acc[(it+2)%3] (skipped on the last iteration — dead).
#pragma unroll
    for (int it = 1; it < NUM_ITERS; ++it) {
        const int gb = it % 3, sb = (it + 1) % 3, rb = (it + 2) % 3;
#pragma unroll
        for (int p = 0; p < BPB; ++p) {
            float vcs[MAXD];
            float mn1 = 1e38f, mn2 = 1e38f;
            unsigned sx = 0u;  bool zr = false;
#pragma unroll
            for (int d = 0; d < MAXD; ++d) {
                if (d < dm) {
                    float vc = softc[p][d]
                             + (float)acc[p][gb][cols[d]] * FXI - cv[p][d];
                    vcs[d] = vc;
                    float a = fminf(fabsf(vc), 1e30f);
                    if (a < mn1) { mn2 = mn1; mn1 = a; }
                    else if (a < mn2) { mn2 = a; }
                    sx ^= (__float_as_uint(vc) & 0x80000000u);
                    zr |= (vc == 0.f);
                }
            }
            const float zmul = zr ? 0.f : alpha;
#pragma unroll
            for (int d = 0; d < MAXD; ++d) {
                if (d < dm) {
                    float vc  = vcs[d];
                    float a   = fminf(fabsf(vc), 1e30f);
                    float res = (a > mn1) ? mn1 : mn2;     // exclude-self min
                    unsigned o = sx ^ (__float_as_uint(vc) & 0x80000000u);
                    float v   = res * zmul;
                    float cvn = __uint_as_float(__float_as_uint(v) ^ o);
                    cv[p][d] = cvn;
                    atomicAdd(&acc[p][sb][cols[d]], __float2int_rn(cvn * FXS));
                }
            }
        }
        if (it != NUM_ITERS - 1) {
            acc[0][rb][n0] = 0; acc[0][rb][n1] = 0;
            acc[1][rb][n0] = 0; acc[1][rb][n1] = 0;
        }
        __syncthreads();
    }

    // ---- posterior LLRs from the last scatter buffer
    const int fb = NUM_ITERS % 3;
    out[ b0      * N_VAR + n0] = s00 + (float)acc[0][fb][n0] * FXI;
    out[ b0      * N_VAR + n1] = s01 + (float)acc[0][fb][n1] * FXI;
    out[(b0 + 1) * N_VAR + n0] = s10 + (float)acc[1][fb][n0] * FXI;
    out[(b0 + 1) * N_VAR + n1] = s11 + (float)acc[1][fb][n1] * FXI;
}

// ---------------------------------------------------------------------------
extern "C" void kernel_launch(void* const* d_in, const int* in_sizes, int n_in,
                              void* d_out, int out_size, void* d_ws, size_t ws_size,
                              hipStream_t stream)
{
    const float* soft_input   = (const float*)d_in[0];
    const float* check_weight = (const float*)d_in[1];
    const int*   H            = (const int*)d_in[2];
    float*       out          = (float*)d_out;

    int* deg        = (int*)d_ws;                  // M
    int* row_cols_T = deg + M_CHECK;               // MAXD * M (col-major)

    build_rows_kernel<<<M_CHECK / 4, 256, 0, stream>>>(H, deg, row_cols_T);
    decode_kernel<<<BATCH / BPB, 1024, 0, stream>>>(
        soft_input, check_weight, deg, row_cols_T, out);
}

// Round 6
// 27.132 us; speedup vs baseline: 1.0989x; 1.0989x over previous
//
#include <hip/hip_runtime.h>
#include <hip/hip_bf16.h>

// LDPC normalized min-sum decoder, B=8, M=1024 checks, N=2048 vars, deg ~8.
// Round 5 -> 6: revert the 2-batches-per-block experiment (decode is
// CU-local LDS-throughput-bound; doubling per-CU work doubled time). Back to
// 8 blocks x 1 batch. Keep: peeled iteration 0, dead-reset skip. New: 512
// threads x 2 rows/thread — same per-CU LDS lane-ops, half the waves per
// barrier, deeper per-wave issue queues.

#define M_CHECK 1024
#define N_VAR   2048
#define BATCH   8
#define THREADS 512
#define RPT     2                // rows per thread (same batch)
#define MAXD    12               // max check-row degree (actual 8..~10)
#define NUM_ITERS 5
#define FXS 16384.0f             // Q14 fixed-point scale
#define FXI (1.0f / 16384.0f)

// ---------------------------------------------------------------------------
// Kernel A: wave-per-row ordered compaction of dense H -> deg, row_cols_T
// (column-major [MAXD][M] for coalesced decode loads). int4-vectorized,
// deterministic ballot/popcount ranking.
__global__ __launch_bounds__(256) void build_rows_kernel(
    const int* __restrict__ H, int* __restrict__ deg,
    int* __restrict__ row_cols_T)
{
    const int m    = blockIdx.x * 4 + (threadIdx.x >> 6);   // wave per row
    const int lane = threadIdx.x & 63;
    const unsigned long long below = (1ULL << lane) - 1ULL;
    const int4* __restrict__ H4 = (const int4*)(H + m * N_VAR);

    int base = 0;
    for (int c = 0; c < N_VAR; c += 256) {                  // 256 cols per pass
        int4 h = H4[(c >> 2) + lane];
        unsigned long long m0 = __ballot(h.x != 0);
        unsigned long long m1 = __ballot(h.y != 0);
        unsigned long long m2 = __ballot(h.z != 0);
        unsigned long long m3 = __ballot(h.w != 0);
        int pb = __popcll(m0 & below) + __popcll(m1 & below)
               + __popcll(m2 & below) + __popcll(m3 & below);
        int b0 = (int)((m0 >> lane) & 1);
        int b1 = (int)((m1 >> lane) & 1);
        int b2 = (int)((m2 >> lane) & 1);
        int col = c + 4 * lane;
        int r = base + pb;
        if (h.x) { if (r < MAXD) row_cols_T[r * M_CHECK + m] = col; }
        r += b0;
        if (h.y) { if (r < MAXD) row_cols_T[r * M_CHECK + m] = col + 1; }
        r += b1;
        if (h.z) { if (r < MAXD) row_cols_T[r * M_CHECK + m] = col + 2; }
        r += b2;
        if (h.w) { if (r < MAXD) row_cols_T[r * M_CHECK + m] = col + 3; }
        base += __popcll(m0) + __popcll(m1) + __popcll(m2) + __popcll(m3);
    }
    if (lane == 0) deg[m] = (base < MAXD) ? base : MAXD;
}

// ---------------------------------------------------------------------------
// Kernel B: full decode, one block per batch, 512 threads x 2 rows each.
// cv in registers; column sums via Q14 integer LDS atomics (native
// ds_add_u32, commutative -> deterministic) into 3 rotating accumulators.
__global__ __launch_bounds__(THREADS) void decode_kernel(
    const float* __restrict__ soft_input, const float* __restrict__ check_weight,
    const int* __restrict__ deg, const int* __restrict__ row_cols_T,
    float* __restrict__ out)
{
    __shared__ int   acc[3][N_VAR];    // 24 KB fixed-point column sums
    __shared__ float soft_s[N_VAR];    //  8 KB

    const int b = blockIdx.x;
    const int t = threadIdx.x;
    const float alpha = log1pf(expf(check_weight[0]));   // softplus(w)

    // ---- init: 4 columns per thread
    float sofr[4];
#pragma unroll
    for (int k = 0; k < 4; ++k) {
        int n = t + k * THREADS;
        float s = soft_input[b * N_VAR + n];
        sofr[k] = s;
        soft_s[n] = s;
        acc[0][n] = 0; acc[1][n] = 0; acc[2][n] = 0;
    }

    // ---- row state: 2 rows per thread (t and t+512)
    int dm_[RPT];
    int cols[RPT][MAXD];
#pragma unroll
    for (int p = 0; p < RPT; ++p) {
        const int m = t + p * THREADS;
        dm_[p] = deg[m];
#pragma unroll
        for (int d = 0; d < MAXD; ++d)
            cols[p][d] = (d < dm_[p]) ? row_cols_T[d * M_CHECK + m] : 0;
    }
    __syncthreads();

    // per-edge soft inputs (registers; one-time LDS gather)
    float softc[RPT][MAXD];
#pragma unroll
    for (int p = 0; p < RPT; ++p)
#pragma unroll
        for (int d = 0; d < MAXD; ++d)
            softc[p][d] = (d < dm_[p]) ? soft_s[cols[p][d]] : 0.f;

    float cv[RPT][MAXD];

    // ---- iteration 0 (peeled): cv=0 and acc=0, so vc = softc. No gather.
#pragma unroll
    for (int p = 0; p < RPT; ++p) {
        const int dm = dm_[p];
        float mn1 = 1e38f, mn2 = 1e38f;
        unsigned sx = 0u;  bool zr = false;
#pragma unroll
        for (int d = 0; d < MAXD; ++d) {
            if (d < dm) {
                float vc = softc[p][d];
                float a  = fminf(fabsf(vc), 1e30f);
                if (a < mn1) { mn2 = mn1; mn1 = a; }
                else if (a < mn2) { mn2 = a; }
                sx ^= (__float_as_uint(vc) & 0x80000000u);
                zr |= (vc == 0.f);
            }
        }
        const float zmul = zr ? 0.f : alpha;
#pragma unroll
        for (int d = 0; d < MAXD; ++d) {
            if (d < dm) {
                float vc  = softc[p][d];
                float a   = fminf(fabsf(vc), 1e30f);
                float res = (a > mn1) ? mn1 : mn2;         // exclude-self min
                unsigned o = sx ^ (__float_as_uint(vc) & 0x80000000u);
                float v   = res * zmul;                    // >= 0
                float cvn = __uint_as_float(__float_as_uint(v) ^ o);
                cv[p][d] = cvn;
                atomicAdd(&acc[1][cols[p][d]], __float2int_rn(cvn * FXS));
            }
        }
    }
    __syncthreads();

    // ---- iterations 1..4: gather acc[it%3], scatter acc[(it+1)%3],
    //      reset acc[(it+2)%3] (skipped on the last iteration — dead).
#pragma unroll
    for (int it = 1; it < NUM_ITERS; ++it) {
        const int gb = it % 3, sb = (it + 1) % 3, rb = (it + 2) % 3;
#pragma unroll
        for (int p = 0; p < RPT; ++p) {
            const int dm = dm_[p];
            float vcs[MAXD];
            float mn1 = 1e38f, mn2 = 1e38f;
            unsigned sx = 0u;  bool zr = false;
#pragma unroll
            for (int d = 0; d < MAXD; ++d) {
                if (d < dm) {
                    float vc = softc[p][d]
                             + (float)acc[gb][cols[p][d]] * FXI - cv[p][d];
                    vcs[d] = vc;
                    float a = fminf(fabsf(vc), 1e30f);
                    if (a < mn1) { mn2 = mn1; mn1 = a; }
                    else if (a < mn2) { mn2 = a; }
                    sx ^= (__float_as_uint(vc) & 0x80000000u);
                    zr |= (vc == 0.f);
                }
            }
            const float zmul = zr ? 0.f : alpha;
#pragma unroll
            for (int d = 0; d < MAXD; ++d) {
                if (d < dm) {
                    float vc  = vcs[d];
                    float a   = fminf(fabsf(vc), 1e30f);
                    float res = (a > mn1) ? mn1 : mn2;     // exclude-self min
                    unsigned o = sx ^ (__float_as_uint(vc) & 0x80000000u);
                    float v   = res * zmul;
                    float cvn = __uint_as_float(__float_as_uint(v) ^ o);
                    cv[p][d] = cvn;
                    atomicAdd(&acc[sb][cols[p][d]], __float2int_rn(cvn * FXS));
                }
            }
        }
        if (it != NUM_ITERS - 1) {
#pragma unroll
            for (int k = 0; k < 4; ++k)
                acc[rb][t + k * THREADS] = 0;
        }
        __syncthreads();
    }

    // ---- posterior LLRs from the last scatter buffer
    const int fb = NUM_ITERS % 3;
#pragma unroll
    for (int k = 0; k < 4; ++k) {
        int n = t + k * THREADS;
        out[b * N_VAR + n] = sofr[k] + (float)acc[fb][n] * FXI;
    }
}

// ---------------------------------------------------------------------------
extern "C" void kernel_launch(void* const* d_in, const int* in_sizes, int n_in,
                              void* d_out, int out_size, void* d_ws, size_t ws_size,
                              hipStream_t stream)
{
    const float* soft_input   = (const float*)d_in[0];
    const float* check_weight = (const float*)d_in[1];
    const int*   H            = (const int*)d_in[2];
    float*       out          = (float*)d_out;

    int* deg        = (int*)d_ws;                  // M
    int* row_cols_T = deg + M_CHECK;               // MAXD * M (col-major)

    build_rows_kernel<<<M_CHECK / 4, 256, 0, stream>>>(H, deg, row_cols_T);
    decode_kernel<<<BATCH, THREADS, 0, stream>>>(
        soft_input, check_weight, deg, row_cols_T, out);
}

// Round 7
// 21.676 us; speedup vs baseline: 1.3755x; 1.2517x over previous
//
#include <hip/hip_runtime.h>
#include <hip/hip_bf16.h>

// LDPC normalized min-sum decoder, B=8, M=1024 checks, N=2048 vars, deg ~8.
// Round 6 -> 7: revert to round-4 partition (8 blocks x 1024 thr, 1 row/thr;
// LDS pipe saturates at 16 waves, starves at 8). Keep only strict work
// removals: peeled iteration 0, wave-uniform __any skip of the d>=8 degree
// tail (~96% of rows have deg 8), separate named accumulator arrays for
// scheduler freedom, dead-init/dead-reset elimination.

#define M_CHECK 1024
#define N_VAR   2048
#define BATCH   8
#define MAXD    12               // max supported check-row degree (actual <= ~10)
#define NUM_ITERS 5
#define FXS 16384.0f             // Q14 fixed-point scale
#define FXI (1.0f / 16384.0f)

// ---------------------------------------------------------------------------
// Kernel A: wave-per-row ordered compaction of dense H -> deg, row_cols_T
// (column-major [MAXD][M] for coalesced decode loads). int4-vectorized,
// deterministic ballot/popcount ranking.
__global__ __launch_bounds__(256) void build_rows_kernel(
    const int* __restrict__ H, int* __restrict__ deg,
    int* __restrict__ row_cols_T)
{
    const int m    = blockIdx.x * 4 + (threadIdx.x >> 6);   // wave per row
    const int lane = threadIdx.x & 63;
    const unsigned long long below = (1ULL << lane) - 1ULL;
    const int4* __restrict__ H4 = (const int4*)(H + m * N_VAR);

    int base = 0;
    for (int c = 0; c < N_VAR; c += 256) {                  // 256 cols per pass
        int4 h = H4[(c >> 2) + lane];
        unsigned long long m0 = __ballot(h.x != 0);
        unsigned long long m1 = __ballot(h.y != 0);
        unsigned long long m2 = __ballot(h.z != 0);
        unsigned long long m3 = __ballot(h.w != 0);
        int pb = __popcll(m0 & below) + __popcll(m1 & below)
               + __popcll(m2 & below) + __popcll(m3 & below);
        int b0 = (int)((m0 >> lane) & 1);
        int b1 = (int)((m1 >> lane) & 1);
        int b2 = (int)((m2 >> lane) & 1);
        int col = c + 4 * lane;
        int r = base + pb;
        if (h.x) { if (r < MAXD) row_cols_T[r * M_CHECK + m] = col; }
        r += b0;
        if (h.y) { if (r < MAXD) row_cols_T[r * M_CHECK + m] = col + 1; }
        r += b1;
        if (h.z) { if (r < MAXD) row_cols_T[r * M_CHECK + m] = col + 2; }
        r += b2;
        if (h.w) { if (r < MAXD) row_cols_T[r * M_CHECK + m] = col + 3; }
        base += __popcll(m0) + __popcll(m1) + __popcll(m2) + __popcll(m3);
    }
    if (lane == 0) deg[m] = (base < MAXD) ? base : MAXD;
}

// ---------------------------------------------------------------------------
// One decode iteration: gather from ACCG, min/submin + sign, scatter to ACCS,
// optionally reset ACCR. d>=8 tail blocks are skipped by wave-uniform __any.
#define DECODE_ITER(ACCG, ACCS, DO_RESET, ACCR)                              \
  {                                                                          \
    float vcs[MAXD];                                                         \
    float mn1 = 1e38f, mn2 = 1e38f;                                          \
    unsigned sx = 0u; bool zr = false;                                       \
    _Pragma("unroll")                                                        \
    for (int d = 0; d < MAXD; ++d) {                                         \
      vcs[d] = 0.f;                                                          \
      if (d < 8 || __any(dm > d)) {                                          \
        if (d < dm) {                                                        \
          float vc = softc[d] + (float)ACCG[cols[d]] * FXI - cv[d];          \
          vcs[d] = vc;                                                       \
          float a = fminf(fabsf(vc), 1e30f);                                 \
          if (a < mn1) { mn2 = mn1; mn1 = a; }                               \
          else if (a < mn2) { mn2 = a; }                                     \
          sx ^= (__float_as_uint(vc) & 0x80000000u);                         \
          zr |= (vc == 0.f);                                                 \
        }                                                                    \
      }                                                                      \
    }                                                                        \
    const float zmul = zr ? 0.f : alpha;                                     \
    _Pragma("unroll")                                                        \
    for (int d = 0; d < MAXD; ++d) {                                         \
      if (d < 8 || __any(dm > d)) {                                          \
        if (d < dm) {                                                        \
          float vc  = vcs[d];                                                \
          float a   = fminf(fabsf(vc), 1e30f);                               \
          float res = (a > mn1) ? mn1 : mn2;   /* exclude-self min */        \
          unsigned o = sx ^ (__float_as_uint(vc) & 0x80000000u);             \
          float v   = res * zmul;              /* >= 0 */                    \
          float cvn = __uint_as_float(__float_as_uint(v) ^ o);               \
          cv[d] = cvn;                                                       \
          atomicAdd(&ACCS[cols[d]], __float2int_rn(cvn * FXS));              \
        }                                                                    \
      }                                                                      \
    }                                                                        \
    if (DO_RESET) { ACCR[n0] = 0; ACCR[n1] = 0; }                            \
    __syncthreads();                                                         \
  }

// ---------------------------------------------------------------------------
// Kernel B: full decode, one block per batch, 1024 threads, 1 row/thread.
// cv in registers; column sums via Q14 integer LDS atomics (native
// ds_add_u32, commutative -> deterministic) into 3 rotating accumulators.
__global__ __launch_bounds__(1024) void decode_kernel(
    const float* __restrict__ soft_input, const float* __restrict__ check_weight,
    const int* __restrict__ deg, const int* __restrict__ row_cols_T,
    float* __restrict__ out)
{
    __shared__ int   acc0[N_VAR];      // 8 KB each
    __shared__ int   acc1[N_VAR];
    __shared__ int   acc2[N_VAR];
    __shared__ float soft_s[N_VAR];

    const int b = blockIdx.x;
    const int t = threadIdx.x;
    const float alpha = log1pf(expf(check_weight[0]));   // softplus(w)

    const int n0 = t, n1 = t + 1024;
    const float s0 = soft_input[b * N_VAR + n0];
    const float s1 = soft_input[b * N_VAR + n1];
    soft_s[n0] = s0;  soft_s[n1] = s1;
    acc1[n0] = 0; acc1[n1] = 0;        // peel scatters into acc1
    acc2[n0] = 0; acc2[n1] = 0;        // it=1 scatters into acc2
    // acc0 needs no init: reset at it=1, first scattered at it=2.

    const int dm = deg[t];
    int cols[MAXD];
#pragma unroll
    for (int d = 0; d < MAXD; ++d)
        cols[d] = (d < dm) ? row_cols_T[d * M_CHECK + t] : 0;   // coalesced
    __syncthreads();

    // per-edge soft inputs (registers; one-time LDS gather)
    float softc[MAXD];
#pragma unroll
    for (int d = 0; d < MAXD; ++d)
        softc[d] = (d < dm) ? soft_s[cols[d]] : 0.f;

    float cv[MAXD];

    // ---- iteration 0 (peeled): cv=0, acc=0 -> vc = softc. No gather.
    {
        float mn1 = 1e38f, mn2 = 1e38f;
        unsigned sx = 0u; bool zr = false;
#pragma unroll
        for (int d = 0; d < MAXD; ++d) {
            if (d < 8 || __any(dm > d)) {
                if (d < dm) {
                    float vc = softc[d];
                    float a  = fminf(fabsf(vc), 1e30f);
                    if (a < mn1) { mn2 = mn1; mn1 = a; }
                    else if (a < mn2) { mn2 = a; }
                    sx ^= (__float_as_uint(vc) & 0x80000000u);
                    zr |= (vc == 0.f);
                }
            }
        }
        const float zmul = zr ? 0.f : alpha;
#pragma unroll
        for (int d = 0; d < MAXD; ++d) {
            if (d < 8 || __any(dm > d)) {
                if (d < dm) {
                    float vc  = softc[d];
                    float a   = fminf(fabsf(vc), 1e30f);
                    float res = (a > mn1) ? mn1 : mn2;
                    unsigned o = sx ^ (__float_as_uint(vc) & 0x80000000u);
                    float v   = res * zmul;
                    float cvn = __uint_as_float(__float_as_uint(v) ^ o);
                    cv[d] = cvn;
                    atomicAdd(&acc1[cols[d]], __float2int_rn(cvn * FXS));
                }
            }
        }
    }
    __syncthreads();

    // ---- iterations 1..4 (rotation unrolled with named arrays)
    DECODE_ITER(acc1, acc2, true,  acc0)   // it=1
    DECODE_ITER(acc2, acc0, true,  acc1)   // it=2
    DECODE_ITER(acc0, acc1, true,  acc2)   // it=3
    DECODE_ITER(acc1, acc2, false, acc0)   // it=4 (reset dead)

    // ---- posterior LLRs from the last scatter buffer (acc2)
    out[b * N_VAR + n0] = s0 + (float)acc2[n0] * FXI;
    out[b * N_VAR + n1] = s1 + (float)acc2[n1] * FXI;
}

// ---------------------------------------------------------------------------
extern "C" void kernel_launch(void* const* d_in, const int* in_sizes, int n_in,
                              void* d_out, int out_size, void* d_ws, size_t ws_size,
                              hipStream_t stream)
{
    const float* soft_input   = (const float*)d_in[0];
    const float* check_weight = (const float*)d_in[1];
    const int*   H            = (const int*)d_in[2];
    float*       out          = (float*)d_out;

    int* deg        = (int*)d_ws;                  // M
    int* row_cols_T = deg + M_CHECK;               // MAXD * M (col-major)

    build_rows_kernel<<<M_CHECK / 4, 256, 0, stream>>>(H, deg, row_cols_T);
    decode_kernel<<<BATCH, 1024, 0, stream>>>(
        soft_input, check_weight, deg, row_cols_T, out);
}